// Round 13
// baseline (179.567 us; speedup 1.0000x reference)
//
#include <hip/hip_runtime.h>
#include <math.h>

#define NFFT  4096
#define MHALF 2048   // complex FFT size (N/2)
#define HOPSZ 1024
#define LX    441000
#define NB    32
#define NF    431
#define NK    2049
#define NFPB  10            // frames per block (2 per wave, 5 waves)
#define FBLK  44            // ceil(431/10)
#define NWG5  (NB * FBLK)   // 1408
#define CH5   (NWG5 / 8)    // 176, exact

// Within-slice swizzle: XOR bits 7..4 into 3..0 (bijective on [0,2048)).
#define SW(A) ((A) ^ (((A) >> 4) & 0xF))
// Wave-local ordering fence.
#define WAVESYNC() do { asm volatile("s_waitcnt lgkmcnt(0)" ::: "memory"); \
                        __builtin_amdgcn_sched_barrier(0); } while (0)

typedef __fp16 half2v __attribute__((ext_vector_type(2)));

__device__ __forceinline__ float2 cadd(float2 a, float2 b){ return make_float2(a.x+b.x, a.y+b.y); }
__device__ __forceinline__ float2 csub(float2 a, float2 b){ return make_float2(a.x-b.x, a.y-b.y); }
__device__ __forceinline__ float2 cmul(float2 a, float2 b){
  return make_float2(fmaf(a.x, b.x, -(a.y*b.y)), fmaf(a.x, b.y, a.y*b.x));
}
#define STH(ptr, idx, v) (ptr)[idx] = __builtin_amdgcn_cvt_pkrtz((v).x, (v).y)
__device__ __forceinline__ float2 ldh(const half2v* __restrict__ X, int idx) {
  half2v h = X[idx];
  return make_float2((float)h.x, (float)h.y);
}

// cos/sin(pi*n/16), n = 0..21; W32^n = (C[n], -S[n])
constexpr float W32C[22] = {
  1.0f, 0.98078528040323f, 0.92387953251129f, 0.83146961230255f, 0.70710678118655f,
  0.55557023301960f, 0.38268343236509f, 0.19509032201613f, 0.0f, -0.19509032201613f,
  -0.38268343236509f, -0.55557023301960f, -0.70710678118655f, -0.83146961230255f,
  -0.92387953251129f, -0.98078528040323f, -1.0f, -0.98078528040323f,
  -0.92387953251129f, -0.83146961230255f, -0.70710678118655f, -0.55557023301960f };
constexpr float W32S[22] = {
  0.0f, 0.19509032201613f, 0.38268343236509f, 0.55557023301960f, 0.70710678118655f,
  0.83146961230255f, 0.92387953251129f, 0.98078528040323f, 1.0f, 0.98078528040323f,
  0.92387953251129f, 0.83146961230255f, 0.70710678118655f, 0.55557023301960f,
  0.38268343236509f, 0.19509032201613f, 0.0f, -0.19509032201613f,
  -0.38268343236509f, -0.55557023301960f, -0.70710678118655f, -0.83146961230255f };

template<int N> __device__ __forceinline__ float2 w32m(float2 z) {
  if constexpr (N == 0) { return z; }
  else if constexpr (N == 8) { return make_float2(z.y, -z.x); }   // *(-i)
  else {
    constexpr float c = W32C[N];
    constexpr float s = W32S[N];
    return make_float2(fmaf(z.x, c, z.y * s), fmaf(z.y, c, -(z.x * s)));
  }
}

// ws layout (floats): [0,4096) window*scale | [4096,6144) exp(-2pi i t/2048), t<1024
//                     | [6144,10242) exp(-2pi i k/4096), k<=2048
__global__ void stft_init(float* __restrict__ ws) {
  int i = blockIdx.x * blockDim.x + threadIdx.x;
  const double PI = 3.14159265358979323846;
  if (i < 4096) {
    double w = 0.5 * (1.0 - cos(2.0 * PI * (double)i / 4096.0)) * (1.0 / 64.0);
    ws[i] = (float)w;
  }
  if (i < 1024) {
    double a = -2.0 * PI * (double)i / 2048.0;
    ws[4096 + 2 * i]     = (float)cos(a);
    ws[4096 + 2 * i + 1] = (float)sin(a);
  }
  if (i < 2049) {
    double a = -2.0 * PI * (double)i / 4096.0;
    ws[6144 + 2 * i]     = (float)cos(a);
    ws[6144 + 2 * i + 1] = (float)sin(a);
  }
}

// 8-point DFT core: B[u] = sum_m a[m] * W8^{um}
__device__ __forceinline__ void dft8(const float2* a, float2* B) {
  float2 t0 = cadd(a[0], a[4]), t1 = csub(a[0], a[4]);
  float2 t2 = cadd(a[2], a[6]), t3 = csub(a[2], a[6]);
  float2 t4 = cadd(a[1], a[5]), t5 = csub(a[1], a[5]);
  float2 t6 = cadd(a[3], a[7]), t7 = csub(a[3], a[7]);
  const float K = 0.70710678118654752f;
  float2 wt5  = make_float2(K * (t5.x + t5.y), K * (t5.y - t5.x));   // W8   * t5
  float2 w3t7 = make_float2(K * (t7.y - t7.x), -K * (t7.x + t7.y));  // W8^3 * t7
  float2 wt7  = make_float2(K * (t7.x + t7.y), K * (t7.y - t7.x));   // W8   * t7
  float2 w3t5 = make_float2(K * (t5.y - t5.x), -K * (t5.x + t5.y));  // W8^3 * t5
  float2 e0 = cadd(t0, t2), e1 = csub(t0, t2);
  float2 f0 = cadd(t4, t6), f1 = csub(t4, t6);
  B[0] = cadd(e0, f0);
  B[4] = csub(e0, f0);
  B[2] = make_float2(e1.x + f1.y, e1.y - f1.x);
  B[6] = make_float2(e1.x - f1.y, e1.y + f1.x);
  float2 g0 = make_float2(t1.x + t3.y, t1.y - t3.x);
  float2 g1 = make_float2(t1.x - t3.y, t1.y + t3.x);
  float2 h0 = cadd(wt5, w3t7);
  float2 h1 = cadd(wt7, w3t5);
  B[1] = cadd(g0, h0);
  B[5] = csub(g0, h0);
  B[3] = cadd(g1, h1);
  B[7] = csub(g1, h1);
}

// Radix-8 Stockham DIF butterfly j (span S), N=2048: twiddled stores to slice.
template<int S>
__device__ __forceinline__ void bf8(half2v* __restrict__ X, int sxor,
                                    const float2* __restrict__ twg,
                                    int j, const float2* a) {
  const int q = j & (S - 1);
  const int t = j - q;
  float2 B[8];
  dft8(a, B);
  float2 w1 = twg[t];          // exp(-2pi i t/2048), t < 256
  float2 w2 = cmul(w1, w1);
  float2 w3 = cmul(w2, w1);
  float2 w4 = cmul(w2, w2);
  float2 w5 = cmul(w3, w2);
  float2 w6 = cmul(w3, w3);
  float2 w7 = cmul(w4, w3);
  const int o = q + 8 * t;
  STH(X, SW(o) ^ sxor, B[0]);
  { float2 v = cmul(w1, B[1]); STH(X, SW(o + S)     ^ sxor, v); }
  { float2 v = cmul(w2, B[2]); STH(X, SW(o + 2 * S) ^ sxor, v); }
  { float2 v = cmul(w3, B[3]); STH(X, SW(o + 3 * S) ^ sxor, v); }
  { float2 v = cmul(w4, B[4]); STH(X, SW(o + 4 * S) ^ sxor, v); }
  { float2 v = cmul(w5, B[5]); STH(X, SW(o + 5 * S) ^ sxor, v); }
  { float2 v = cmul(w6, B[6]); STH(X, SW(o + 6 * S) ^ sxor, v); }
  { float2 v = cmul(w7, B[7]); STH(X, SW(o + 7 * S) ^ sxor, v); }
}

// load + window one frame into a[4][8] (lane l owns complex idx l+64r+256m)
__device__ __forceinline__ void loadwin(float2 (*a)[8], const float* __restrict__ xb,
                                        int f, int l,
                                        const float2* __restrict__ winv,
                                        const float* __restrict__ win) {
  const int base = f * HOPSZ - MHALF;
  if (base >= 0 && base + NFFT <= LX) {
    const float2* xv = (const float2*)(xb + base);  // base even -> aligned
#pragma unroll
    for (int r = 0; r < 4; ++r) {
      const int j = l + (r << 6);
#pragma unroll
      for (int m = 0; m < 8; ++m) {
        const int idx = j + (m << 8);
        float2 v = xv[idx];
        float2 w = winv[idx];
        a[r][m] = make_float2(v.x * w.x, v.y * w.y);
      }
    }
  } else {  // edge frames: per-element reflect
#pragma unroll
    for (int r = 0; r < 4; ++r) {
      const int j = l + (r << 6);
#pragma unroll
      for (int m = 0; m < 8; ++m) {
        const int idx = j + (m << 8);
        int s0 = base + 2 * idx;
        int s1 = s0 + 1;
        s0 = (s0 < 0) ? -s0 : ((s0 >= LX) ? (2 * LX - 2 - s0) : s0);
        s1 = (s1 < 0) ? -s1 : ((s1 >= LX) ? (2 * LX - 2 - s1) : s1);
        a[r][m] = make_float2(xb[s0] * win[2 * idx], xb[s1] * win[2 * idx + 1]);
      }
    }
  }
}

// Final radix-32 stage (S=64): externally twiddle-free; internal twiddles are
// compile-time W32 constants. dd = 32 regs after the dft4-over-m2 pass.
#define VBLK(dd, slp, sx, V) do {                                     \
    float2 tt[8], BB[8];                                              \
    tt[0] = dd[8*(V)+0];                                              \
    tt[1] = w32m<1*(V)>(dd[8*(V)+1]);                                 \
    tt[2] = w32m<2*(V)>(dd[8*(V)+2]);                                 \
    tt[3] = w32m<3*(V)>(dd[8*(V)+3]);                                 \
    tt[4] = w32m<4*(V)>(dd[8*(V)+4]);                                 \
    tt[5] = w32m<5*(V)>(dd[8*(V)+5]);                                 \
    tt[6] = w32m<6*(V)>(dd[8*(V)+6]);                                 \
    tt[7] = w32m<7*(V)>(dd[8*(V)+7]);                                 \
    dft8(tt, BB);                                                     \
    STH(slp, SW(l + (((V) +  0) << 6)) ^ sx, BB[0]);                  \
    STH(slp, SW(l + (((V) +  4) << 6)) ^ sx, BB[1]);                  \
    STH(slp, SW(l + (((V) +  8) << 6)) ^ sx, BB[2]);                  \
    STH(slp, SW(l + (((V) + 12) << 6)) ^ sx, BB[3]);                  \
    STH(slp, SW(l + (((V) + 16) << 6)) ^ sx, BB[4]);                  \
    STH(slp, SW(l + (((V) + 20) << 6)) ^ sx, BB[5]);                  \
    STH(slp, SW(l + (((V) + 24) << 6)) ^ sx, BB[6]);                  \
    STH(slp, SW(l + (((V) + 28) << 6)) ^ sx, BB[7]);                  \
  } while (0)

#define DFT4PASS(dd) do {                                             \
    _Pragma("unroll")                                                 \
    for (int m1 = 0; m1 < 8; ++m1) {                                  \
      float2 p0 = dd[m1], p1 = dd[m1 + 8], p2 = dd[m1 + 16], p3 = dd[m1 + 24]; \
      float2 e0 = cadd(p0, p2), e1 = csub(p0, p2);                    \
      float2 o0 = cadd(p1, p3), o1 = csub(p1, p3);                    \
      dd[m1]      = cadd(e0, o0);                                     \
      dd[m1 + 8]  = make_float2(e1.x + o1.y, e1.y - o1.x);            \
      dd[m1 + 16] = csub(e0, o0);                                     \
      dd[m1 + 24] = make_float2(e1.x - o1.y, e1.y + o1.x);            \
    }                                                                 \
  } while (0)

// 5 waves/block, TWO frames per wave (R9 structure, +25% streams/CU).
// 10 fp16 slices (80 KB LDS, 2 blocks/CU = 10 waves). Wave-local fences in
// FFT; one __syncthreads; R9's proven 8B per-frame-slot recomb stores.
__global__ __launch_bounds__(320, 2) void stft_fft(const float* __restrict__ x,
                                                   const float* __restrict__ ws,
                                                   float* __restrict__ out) {
  __shared__ half2v fbuf[NFPB * 2048];   // 80 KB

  const int tid = threadIdx.x;
  const int wid = (blockIdx.x & 7) * CH5 + (blockIdx.x >> 3);
  const int b  = wid / FBLK;
  const int fb = wid - b * FBLK;
  const int f0 = fb * NFPB;
  const int wv = tid >> 6;        // 0..4
  const int l  = tid & 63;
  const int fA = f0 + 2 * wv;     // may exceed NF for fb=43, wv>=1
  const int fB = fA + 1;
  const bool hasA = (fA < NF);    // wave-uniform
  const bool hasB = (fB < NF);    // wave-uniform

  const float*  win  = ws;
  const float2* winv = (const float2*)ws;
  const float2* twg  = (const float2*)(ws + 4096);
  const float2* tw4  = (const float2*)(ws + 6144);
  const float* xb = x + (size_t)b * LX;

  half2v* __restrict__ slA = &fbuf[(2 * wv) * 2048];
  half2v* __restrict__ slB = &fbuf[(2 * wv + 1) * 2048];
  const int sxA = (2 * wv) << 2;
  const int sxB = (2 * wv + 1) << 2;

  if (hasA) {
    // ---- stage 1 (S=1): load+window -> regs -> twiddled LDS (A and B)
    float2 aA[4][8], aB[4][8];
    loadwin(aA, xb, fA, l, winv, win);
    if (hasB) loadwin(aB, xb, fB, l, winv, win);
#pragma unroll
    for (int r = 0; r < 4; ++r) {
      bf8<1>(slA, sxA, twg, l + (r << 6), aA[r]);
      if (hasB) bf8<1>(slB, sxB, twg, l + (r << 6), aB[r]);
    }
    WAVESYNC();

    // ---- stage 2 (S=8): read-all(A,B) -> fence -> write-all(A,B)
#pragma unroll
    for (int r = 0; r < 4; ++r) {
      const int j = l + (r << 6);
#pragma unroll
      for (int m = 0; m < 8; ++m) {
        aA[r][m] = ldh(slA, SW(j + (m << 8)) ^ sxA);
        if (hasB) aB[r][m] = ldh(slB, SW(j + (m << 8)) ^ sxB);
      }
    }
    WAVESYNC();
#pragma unroll
    for (int r = 0; r < 4; ++r) {
      bf8<8>(slA, sxA, twg, l + (r << 6), aA[r]);
      if (hasB) bf8<8>(slB, sxB, twg, l + (r << 6), aB[r]);
    }
    WAVESYNC();

    // ---- stage 3: radix-32 (S=64), lane-disjoint in-place, A and B
    float2 dA[32], dB[32];
#pragma unroll
    for (int m = 0; m < 32; ++m) {
      dA[m] = ldh(slA, SW(l + (m << 6)) ^ sxA);
      if (hasB) dB[m] = ldh(slB, SW(l + (m << 6)) ^ sxB);
    }
    WAVESYNC();
    DFT4PASS(dA);
    VBLK(dA, slA, sxA, 0); VBLK(dA, slA, sxA, 1);
    VBLK(dA, slA, sxA, 2); VBLK(dA, slA, sxA, 3);
    if (hasB) {
      DFT4PASS(dB);
      VBLK(dB, slB, sxB, 0); VBLK(dB, slB, sxB, 1);
      VBLK(dB, slB, sxB, 2); VBLK(dB, slB, sxB, 3);
    }
  }
  __syncthreads();   // the only block-wide barrier (reached by all waves)

  // ---- paired recomb + store: thread -> (k, frame-slot), 8B stores in
  // 80B-contiguous frame runs per k (R9-proven scheme, 10 slots).
  float2* __restrict__ op = (float2*)out;
  const size_t obB = (size_t)b * NK * NF;
  const int s  = tid % NFPB;        // frame slot 0..9
  const int kk = tid / NFPB;        // 0..31
  const int fS = f0 + s;
  const bool act = (fS < NF);
  const half2v* __restrict__ sl2 = &fbuf[s * 2048];
  const int sx2 = s << 2;
#pragma unroll 4
  for (int it = 0; it < 32; ++it) {
    const int k  = kk + (it << 5);            // 0..1023
    const int km = (2048 - k) & 2047;
    float2 zk = ldh(sl2, SW(k)  ^ sx2);
    float2 zm = ldh(sl2, SW(km) ^ sx2);
    float xex = 0.5f * (zk.x + zm.x);
    float xey = 0.5f * (zk.y - zm.y);
    float xox = 0.5f * (zk.y + zm.y);
    float xoy = 0.5f * (zm.x - zk.x);
    float2 w = tw4[k];
    float tx = w.x * xox - w.y * xoy;
    float ty = w.x * xoy + w.y * xox;
    if (act) {
      op[obB + (size_t)k * NF + fS]          = make_float2(xex + tx,  xey + ty);
      op[obB + (size_t)(2048 - k) * NF + fS] = make_float2(xex - tx, -xey + ty);
    }
  }
  if (tid < NFPB && (f0 + tid) < NF) {   // k = 1024: out = conj(z[1024])
    const half2v* slt = &fbuf[tid * 2048];
    float2 zq = ldh(slt, SW(1024) ^ (tid << 2));
    op[obB + (size_t)1024 * NF + (f0 + tid)] = make_float2(zq.x, -zq.y);
  }
}

extern "C" void kernel_launch(void* const* d_in, const int* in_sizes, int n_in,
                              void* d_out, int out_size, void* d_ws, size_t ws_size,
                              hipStream_t stream) {
  const float* x = (const float*)d_in[0];
  float* ws = (float*)d_ws;     // needs 10242 floats (~41 KB)
  float* out = (float*)d_out;
  stft_init<<<16, 256, 0, stream>>>(ws);
  stft_fft<<<NWG5, 320, 0, stream>>>(x, ws, out);
}

// Round 14
// 159.989 us; speedup vs baseline: 1.1224x; 1.1224x over previous
//
#include <hip/hip_runtime.h>
#include <math.h>

#define NFFT  4096
#define MHALF 2048   // complex FFT size (N/2)
#define HOPSZ 1024
#define LX    441000
#define NB    32
#define NF    431
#define NK    2049
#define NFPB  6             // frames per block (2 per wave, 3 waves)
#define FBLK  72            // ceil(431/6)
#define NWG6  (NB * FBLK)   // 2304
#define CH6   (NWG6 / 8)    // 288, exact

// Within-slice swizzle: XOR bits 7..4 into 3..0 (bijective on [0,2048)).
#define SW(A) ((A) ^ (((A) >> 4) & 0xF))
// Wave-local ordering fence.
#define WAVESYNC() do { asm volatile("s_waitcnt lgkmcnt(0)" ::: "memory"); \
                        __builtin_amdgcn_sched_barrier(0); } while (0)

typedef __fp16 half2v __attribute__((ext_vector_type(2)));

__device__ __forceinline__ float2 cadd(float2 a, float2 b){ return make_float2(a.x+b.x, a.y+b.y); }
__device__ __forceinline__ float2 csub(float2 a, float2 b){ return make_float2(a.x-b.x, a.y-b.y); }
__device__ __forceinline__ float2 cmul(float2 a, float2 b){
  return make_float2(fmaf(a.x, b.x, -(a.y*b.y)), fmaf(a.x, b.y, a.y*b.x));
}
#define STH(ptr, idx, v) (ptr)[idx] = __builtin_amdgcn_cvt_pkrtz((v).x, (v).y)
__device__ __forceinline__ float2 ldh(const half2v* __restrict__ X, int idx) {
  half2v h = X[idx];
  return make_float2((float)h.x, (float)h.y);
}

// cos/sin(pi*n/16), n = 0..21; W32^n = (C[n], -S[n])
constexpr float W32C[22] = {
  1.0f, 0.98078528040323f, 0.92387953251129f, 0.83146961230255f, 0.70710678118655f,
  0.55557023301960f, 0.38268343236509f, 0.19509032201613f, 0.0f, -0.19509032201613f,
  -0.38268343236509f, -0.55557023301960f, -0.70710678118655f, -0.83146961230255f,
  -0.92387953251129f, -0.98078528040323f, -1.0f, -0.98078528040323f,
  -0.92387953251129f, -0.83146961230255f, -0.70710678118655f, -0.55557023301960f };
constexpr float W32S[22] = {
  0.0f, 0.19509032201613f, 0.38268343236509f, 0.55557023301960f, 0.70710678118655f,
  0.83146961230255f, 0.92387953251129f, 0.98078528040323f, 1.0f, 0.98078528040323f,
  0.92387953251129f, 0.83146961230255f, 0.70710678118655f, 0.55557023301960f,
  0.38268343236509f, 0.19509032201613f, 0.0f, -0.19509032201613f,
  -0.38268343236509f, -0.55557023301960f, -0.70710678118655f, -0.83146961230255f };

template<int N> __device__ __forceinline__ float2 w32m(float2 z) {
  if constexpr (N == 0) { return z; }
  else if constexpr (N == 8) { return make_float2(z.y, -z.x); }   // *(-i)
  else {
    constexpr float c = W32C[N];
    constexpr float s = W32S[N];
    return make_float2(fmaf(z.x, c, z.y * s), fmaf(z.y, c, -(z.x * s)));
  }
}

// ws layout (floats): [0,4096) window*scale | [4096,6144) exp(-2pi i t/2048), t<1024
//                     | [6144,10242) exp(-2pi i k/4096), k<=2048
__global__ void stft_init(float* __restrict__ ws) {
  int i = blockIdx.x * blockDim.x + threadIdx.x;
  const double PI = 3.14159265358979323846;
  if (i < 4096) {
    double w = 0.5 * (1.0 - cos(2.0 * PI * (double)i / 4096.0)) * (1.0 / 64.0);
    ws[i] = (float)w;
  }
  if (i < 1024) {
    double a = -2.0 * PI * (double)i / 2048.0;
    ws[4096 + 2 * i]     = (float)cos(a);
    ws[4096 + 2 * i + 1] = (float)sin(a);
  }
  if (i < 2049) {
    double a = -2.0 * PI * (double)i / 4096.0;
    ws[6144 + 2 * i]     = (float)cos(a);
    ws[6144 + 2 * i + 1] = (float)sin(a);
  }
}

// 8-point DFT core: B[u] = sum_m a[m] * W8^{um}
__device__ __forceinline__ void dft8(const float2* a, float2* B) {
  float2 t0 = cadd(a[0], a[4]), t1 = csub(a[0], a[4]);
  float2 t2 = cadd(a[2], a[6]), t3 = csub(a[2], a[6]);
  float2 t4 = cadd(a[1], a[5]), t5 = csub(a[1], a[5]);
  float2 t6 = cadd(a[3], a[7]), t7 = csub(a[3], a[7]);
  const float K = 0.70710678118654752f;
  float2 wt5  = make_float2(K * (t5.x + t5.y), K * (t5.y - t5.x));   // W8   * t5
  float2 w3t7 = make_float2(K * (t7.y - t7.x), -K * (t7.x + t7.y));  // W8^3 * t7
  float2 wt7  = make_float2(K * (t7.x + t7.y), K * (t7.y - t7.x));   // W8   * t7
  float2 w3t5 = make_float2(K * (t5.y - t5.x), -K * (t5.x + t5.y));  // W8^3 * t5
  float2 e0 = cadd(t0, t2), e1 = csub(t0, t2);
  float2 f0 = cadd(t4, t6), f1 = csub(t4, t6);
  B[0] = cadd(e0, f0);
  B[4] = csub(e0, f0);
  B[2] = make_float2(e1.x + f1.y, e1.y - f1.x);
  B[6] = make_float2(e1.x - f1.y, e1.y + f1.x);
  float2 g0 = make_float2(t1.x + t3.y, t1.y - t3.x);
  float2 g1 = make_float2(t1.x - t3.y, t1.y + t3.x);
  float2 h0 = cadd(wt5, w3t7);
  float2 h1 = cadd(wt7, w3t5);
  B[1] = cadd(g0, h0);
  B[5] = csub(g0, h0);
  B[3] = cadd(g1, h1);
  B[7] = csub(g1, h1);
}

// Radix-8 Stockham DIF butterfly j (span S), N=2048: twiddled stores to slice.
template<int S>
__device__ __forceinline__ void bf8(half2v* __restrict__ X, int sxor,
                                    const float2* __restrict__ twg,
                                    int j, const float2* a) {
  const int q = j & (S - 1);
  const int t = j - q;
  float2 B[8];
  dft8(a, B);
  float2 w1 = twg[t];          // exp(-2pi i t/2048), t < 256
  float2 w2 = cmul(w1, w1);
  float2 w3 = cmul(w2, w1);
  float2 w4 = cmul(w2, w2);
  float2 w5 = cmul(w3, w2);
  float2 w6 = cmul(w3, w3);
  float2 w7 = cmul(w4, w3);
  const int o = q + 8 * t;
  STH(X, SW(o) ^ sxor, B[0]);
  { float2 v = cmul(w1, B[1]); STH(X, SW(o + S)     ^ sxor, v); }
  { float2 v = cmul(w2, B[2]); STH(X, SW(o + 2 * S) ^ sxor, v); }
  { float2 v = cmul(w3, B[3]); STH(X, SW(o + 3 * S) ^ sxor, v); }
  { float2 v = cmul(w4, B[4]); STH(X, SW(o + 4 * S) ^ sxor, v); }
  { float2 v = cmul(w5, B[5]); STH(X, SW(o + 5 * S) ^ sxor, v); }
  { float2 v = cmul(w6, B[6]); STH(X, SW(o + 6 * S) ^ sxor, v); }
  { float2 v = cmul(w7, B[7]); STH(X, SW(o + 7 * S) ^ sxor, v); }
}

// load + window one frame into a[4][8] (lane l owns complex idx l+64r+256m)
__device__ __forceinline__ void loadwin(float2 (*a)[8], const float* __restrict__ xb,
                                        int f, int l,
                                        const float2* __restrict__ winv,
                                        const float* __restrict__ win) {
  const int base = f * HOPSZ - MHALF;
  if (base >= 0 && base + NFFT <= LX) {
    const float2* xv = (const float2*)(xb + base);  // base even -> aligned
#pragma unroll
    for (int r = 0; r < 4; ++r) {
      const int j = l + (r << 6);
#pragma unroll
      for (int m = 0; m < 8; ++m) {
        const int idx = j + (m << 8);
        float2 v = xv[idx];
        float2 w = winv[idx];
        a[r][m] = make_float2(v.x * w.x, v.y * w.y);
      }
    }
  } else {  // edge frames: per-element reflect
#pragma unroll
    for (int r = 0; r < 4; ++r) {
      const int j = l + (r << 6);
#pragma unroll
      for (int m = 0; m < 8; ++m) {
        const int idx = j + (m << 8);
        int s0 = base + 2 * idx;
        int s1 = s0 + 1;
        s0 = (s0 < 0) ? -s0 : ((s0 >= LX) ? (2 * LX - 2 - s0) : s0);
        s1 = (s1 < 0) ? -s1 : ((s1 >= LX) ? (2 * LX - 2 - s1) : s1);
        a[r][m] = make_float2(xb[s0] * win[2 * idx], xb[s1] * win[2 * idx + 1]);
      }
    }
  }
}

// Final radix-32 stage (S=64): externally twiddle-free; internal twiddles are
// compile-time W32 constants. dd = 32 regs after the dft4-over-m2 pass.
#define VBLK(dd, slp, sx, V) do {                                     \
    float2 tt[8], BB[8];                                              \
    tt[0] = dd[8*(V)+0];                                              \
    tt[1] = w32m<1*(V)>(dd[8*(V)+1]);                                 \
    tt[2] = w32m<2*(V)>(dd[8*(V)+2]);                                 \
    tt[3] = w32m<3*(V)>(dd[8*(V)+3]);                                 \
    tt[4] = w32m<4*(V)>(dd[8*(V)+4]);                                 \
    tt[5] = w32m<5*(V)>(dd[8*(V)+5]);                                 \
    tt[6] = w32m<6*(V)>(dd[8*(V)+6]);                                 \
    tt[7] = w32m<7*(V)>(dd[8*(V)+7]);                                 \
    dft8(tt, BB);                                                     \
    STH(slp, SW(l + (((V) +  0) << 6)) ^ sx, BB[0]);                  \
    STH(slp, SW(l + (((V) +  4) << 6)) ^ sx, BB[1]);                  \
    STH(slp, SW(l + (((V) +  8) << 6)) ^ sx, BB[2]);                  \
    STH(slp, SW(l + (((V) + 12) << 6)) ^ sx, BB[3]);                  \
    STH(slp, SW(l + (((V) + 16) << 6)) ^ sx, BB[4]);                  \
    STH(slp, SW(l + (((V) + 20) << 6)) ^ sx, BB[5]);                  \
    STH(slp, SW(l + (((V) + 24) << 6)) ^ sx, BB[6]);                  \
    STH(slp, SW(l + (((V) + 28) << 6)) ^ sx, BB[7]);                  \
  } while (0)

#define DFT4PASS(dd) do {                                             \
    _Pragma("unroll")                                                 \
    for (int m1 = 0; m1 < 8; ++m1) {                                  \
      float2 p0 = dd[m1], p1 = dd[m1 + 8], p2 = dd[m1 + 16], p3 = dd[m1 + 24]; \
      float2 e0 = cadd(p0, p2), e1 = csub(p0, p2);                    \
      float2 o0 = cadd(p1, p3), o1 = csub(p1, p3);                    \
      dd[m1]      = cadd(e0, o0);                                     \
      dd[m1 + 8]  = make_float2(e1.x + o1.y, e1.y - o1.x);            \
      dd[m1 + 16] = csub(e0, o0);                                     \
      dd[m1 + 24] = make_float2(e1.x - o1.y, e1.y + o1.x);            \
    }                                                                 \
  } while (0)

// 3 waves/block, TWO frames per wave (R9 structure, 18 streams/CU).
// 6 fp16 slices (48 KB LDS -> 3 blocks/CU = 9 waves). Wave-local fences in
// FFT; one __syncthreads; R9's proven 8B per-frame-slot recomb stores.
__global__ __launch_bounds__(192, 2) void stft_fft(const float* __restrict__ x,
                                                   const float* __restrict__ ws,
                                                   float* __restrict__ out) {
  __shared__ half2v fbuf[NFPB * 2048];   // 48 KB

  const int tid = threadIdx.x;
  const int wid = (blockIdx.x & 7) * CH6 + (blockIdx.x >> 3);
  const int b  = wid / FBLK;
  const int fb = wid - b * FBLK;
  const int f0 = fb * NFPB;
  const int wv = tid >> 6;        // 0..2
  const int l  = tid & 63;
  const int fA = f0 + 2 * wv;     // <= 430 always
  const int fB = fA + 1;
  const bool hasB = (fB < NF);    // wave-uniform (false only last block, wv=2)

  const float*  win  = ws;
  const float2* winv = (const float2*)ws;
  const float2* twg  = (const float2*)(ws + 4096);
  const float2* tw4  = (const float2*)(ws + 6144);
  const float* xb = x + (size_t)b * LX;

  half2v* __restrict__ slA = &fbuf[(2 * wv) * 2048];
  half2v* __restrict__ slB = &fbuf[(2 * wv + 1) * 2048];
  const int sxA = (2 * wv) << 2;
  const int sxB = (2 * wv + 1) << 2;

  {
    // ---- stage 1 (S=1): load+window -> regs -> twiddled LDS (A and B)
    float2 aA[4][8], aB[4][8];
    loadwin(aA, xb, fA, l, winv, win);
    if (hasB) loadwin(aB, xb, fB, l, winv, win);
#pragma unroll
    for (int r = 0; r < 4; ++r) {
      bf8<1>(slA, sxA, twg, l + (r << 6), aA[r]);
      if (hasB) bf8<1>(slB, sxB, twg, l + (r << 6), aB[r]);
    }
    WAVESYNC();

    // ---- stage 2 (S=8): read-all(A,B) -> fence -> write-all(A,B)
#pragma unroll
    for (int r = 0; r < 4; ++r) {
      const int j = l + (r << 6);
#pragma unroll
      for (int m = 0; m < 8; ++m) {
        aA[r][m] = ldh(slA, SW(j + (m << 8)) ^ sxA);
        if (hasB) aB[r][m] = ldh(slB, SW(j + (m << 8)) ^ sxB);
      }
    }
    WAVESYNC();
#pragma unroll
    for (int r = 0; r < 4; ++r) {
      bf8<8>(slA, sxA, twg, l + (r << 6), aA[r]);
      if (hasB) bf8<8>(slB, sxB, twg, l + (r << 6), aB[r]);
    }
    WAVESYNC();
  }

  // ---- stage 3: radix-32 (S=64), lane-disjoint in-place, A and B
  {
    float2 dA[32], dB[32];
#pragma unroll
    for (int m = 0; m < 32; ++m) {
      dA[m] = ldh(slA, SW(l + (m << 6)) ^ sxA);
      if (hasB) dB[m] = ldh(slB, SW(l + (m << 6)) ^ sxB);
    }
    WAVESYNC();
    DFT4PASS(dA);
    VBLK(dA, slA, sxA, 0); VBLK(dA, slA, sxA, 1);
    VBLK(dA, slA, sxA, 2); VBLK(dA, slA, sxA, 3);
    if (hasB) {
      DFT4PASS(dB);
      VBLK(dB, slB, sxB, 0); VBLK(dB, slB, sxB, 1);
      VBLK(dB, slB, sxB, 2); VBLK(dB, slB, sxB, 3);
    }
  }
  __syncthreads();   // the only block-wide barrier

  // ---- paired recomb + store: thread -> (k, frame-slot), 8B stores in
  // 48B-contiguous frame runs per k (R9-proven scheme, 6 slots).
  float2* __restrict__ op = (float2*)out;
  const size_t obB = (size_t)b * NK * NF;
  const int s  = tid % NFPB;        // frame slot 0..5
  const int kk = tid / NFPB;        // 0..31 (192 = 6*32 exact)
  const int fS = f0 + s;
  const bool act = (fS < NF);
  const half2v* __restrict__ sl2 = &fbuf[s * 2048];
  const int sx2 = s << 2;
#pragma unroll 4
  for (int it = 0; it < 32; ++it) {
    const int k  = kk + (it << 5);            // 0..1023
    const int km = (2048 - k) & 2047;
    float2 zk = ldh(sl2, SW(k)  ^ sx2);
    float2 zm = ldh(sl2, SW(km) ^ sx2);
    float xex = 0.5f * (zk.x + zm.x);
    float xey = 0.5f * (zk.y - zm.y);
    float xox = 0.5f * (zk.y + zm.y);
    float xoy = 0.5f * (zm.x - zk.x);
    float2 w = tw4[k];
    float tx = w.x * xox - w.y * xoy;
    float ty = w.x * xoy + w.y * xox;
    if (act) {
      op[obB + (size_t)k * NF + fS]          = make_float2(xex + tx,  xey + ty);
      op[obB + (size_t)(2048 - k) * NF + fS] = make_float2(xex - tx, -xey + ty);
    }
  }
  if (tid < NFPB && (f0 + tid) < NF) {   // k = 1024: out = conj(z[1024])
    const half2v* slt = &fbuf[tid * 2048];
    float2 zq = ldh(slt, SW(1024) ^ (tid << 2));
    op[obB + (size_t)1024 * NF + (f0 + tid)] = make_float2(zq.x, -zq.y);
  }
}

extern "C" void kernel_launch(void* const* d_in, const int* in_sizes, int n_in,
                              void* d_out, int out_size, void* d_ws, size_t ws_size,
                              hipStream_t stream) {
  const float* x = (const float*)d_in[0];
  float* ws = (float*)d_ws;     // needs 10242 floats (~41 KB)
  float* out = (float*)d_out;
  stft_init<<<16, 256, 0, stream>>>(ws);
  stft_fft<<<NWG6, 192, 0, stream>>>(x, ws, out);
}

// Round 15
// 129.116 us; speedup vs baseline: 1.3907x; 1.2391x over previous
//
#include <hip/hip_runtime.h>
#include <math.h>

#define NFFT  4096
#define MHALF 2048   // complex FFT size (N/2)
#define HOPSZ 1024
#define LX    441000
#define NB    32
#define NF    431
#define NK    2049
#define NFPB  8             // frames per block (2 per wave, 4 waves)
#define FBLK  54            // ceil(431/8)
#define NWG3  (NB * FBLK)   // 1728
#define CH3   (NWG3 / 8)    // 216, exact

// Within-slice swizzle: XOR bits 7..4 into 3..0 (bijective on [0,2048)).
#define SW(A) ((A) ^ (((A) >> 4) & 0xF))
// Compiler-only ordering fence. HW guarantees same-wave LDS ops execute in
// order (lgkmcnt in-order LDS property), and all cross-lane hazards here are
// intra-wave, so no s_waitcnt drain is needed — only "don't reorder" for the
// compiler. Zero instructions emitted; scheduler may interleave A/B streams.
#define SOFTSYNC() asm volatile("" ::: "memory")

typedef __fp16 half2v __attribute__((ext_vector_type(2)));

__device__ __forceinline__ float2 cadd(float2 a, float2 b){ return make_float2(a.x+b.x, a.y+b.y); }
__device__ __forceinline__ float2 csub(float2 a, float2 b){ return make_float2(a.x-b.x, a.y-b.y); }
__device__ __forceinline__ float2 cmul(float2 a, float2 b){
  return make_float2(fmaf(a.x, b.x, -(a.y*b.y)), fmaf(a.x, b.y, a.y*b.x));
}
#define STH(ptr, idx, v) (ptr)[idx] = __builtin_amdgcn_cvt_pkrtz((v).x, (v).y)
__device__ __forceinline__ float2 ldh(const half2v* __restrict__ X, int idx) {
  half2v h = X[idx];
  return make_float2((float)h.x, (float)h.y);
}

// cos/sin(pi*n/16), n = 0..21; W32^n = (C[n], -S[n])
constexpr float W32C[22] = {
  1.0f, 0.98078528040323f, 0.92387953251129f, 0.83146961230255f, 0.70710678118655f,
  0.55557023301960f, 0.38268343236509f, 0.19509032201613f, 0.0f, -0.19509032201613f,
  -0.38268343236509f, -0.55557023301960f, -0.70710678118655f, -0.83146961230255f,
  -0.92387953251129f, -0.98078528040323f, -1.0f, -0.98078528040323f,
  -0.92387953251129f, -0.83146961230255f, -0.70710678118655f, -0.55557023301960f };
constexpr float W32S[22] = {
  0.0f, 0.19509032201613f, 0.38268343236509f, 0.55557023301960f, 0.70710678118655f,
  0.83146961230255f, 0.92387953251129f, 0.98078528040323f, 1.0f, 0.98078528040323f,
  0.92387953251129f, 0.83146961230255f, 0.70710678118655f, 0.55557023301960f,
  0.38268343236509f, 0.19509032201613f, 0.0f, -0.19509032201613f,
  -0.38268343236509f, -0.55557023301960f, -0.70710678118655f, -0.83146961230255f };

template<int N> __device__ __forceinline__ float2 w32m(float2 z) {
  if constexpr (N == 0) { return z; }
  else if constexpr (N == 8) { return make_float2(z.y, -z.x); }   // *(-i)
  else {
    constexpr float c = W32C[N];
    constexpr float s = W32S[N];
    return make_float2(fmaf(z.x, c, z.y * s), fmaf(z.y, c, -(z.x * s)));
  }
}

// ws layout (floats): [0,4096) window*scale | [4096,6144) exp(-2pi i t/2048), t<1024
//                     | [6144,10242) exp(-2pi i k/4096), k<=2048
__global__ void stft_init(float* __restrict__ ws) {
  int i = blockIdx.x * blockDim.x + threadIdx.x;
  const double PI = 3.14159265358979323846;
  if (i < 4096) {
    double w = 0.5 * (1.0 - cos(2.0 * PI * (double)i / 4096.0)) * (1.0 / 64.0);
    ws[i] = (float)w;
  }
  if (i < 1024) {
    double a = -2.0 * PI * (double)i / 2048.0;
    ws[4096 + 2 * i]     = (float)cos(a);
    ws[4096 + 2 * i + 1] = (float)sin(a);
  }
  if (i < 2049) {
    double a = -2.0 * PI * (double)i / 4096.0;
    ws[6144 + 2 * i]     = (float)cos(a);
    ws[6144 + 2 * i + 1] = (float)sin(a);
  }
}

// 8-point DFT core: B[u] = sum_m a[m] * W8^{um}
__device__ __forceinline__ void dft8(const float2* a, float2* B) {
  float2 t0 = cadd(a[0], a[4]), t1 = csub(a[0], a[4]);
  float2 t2 = cadd(a[2], a[6]), t3 = csub(a[2], a[6]);
  float2 t4 = cadd(a[1], a[5]), t5 = csub(a[1], a[5]);
  float2 t6 = cadd(a[3], a[7]), t7 = csub(a[3], a[7]);
  const float K = 0.70710678118654752f;
  float2 wt5  = make_float2(K * (t5.x + t5.y), K * (t5.y - t5.x));   // W8   * t5
  float2 w3t7 = make_float2(K * (t7.y - t7.x), -K * (t7.x + t7.y));  // W8^3 * t7
  float2 wt7  = make_float2(K * (t7.x + t7.y), K * (t7.y - t7.x));   // W8   * t7
  float2 w3t5 = make_float2(K * (t5.y - t5.x), -K * (t5.x + t5.y));  // W8^3 * t5
  float2 e0 = cadd(t0, t2), e1 = csub(t0, t2);
  float2 f0 = cadd(t4, t6), f1 = csub(t4, t6);
  B[0] = cadd(e0, f0);
  B[4] = csub(e0, f0);
  B[2] = make_float2(e1.x + f1.y, e1.y - f1.x);
  B[6] = make_float2(e1.x - f1.y, e1.y + f1.x);
  float2 g0 = make_float2(t1.x + t3.y, t1.y - t3.x);
  float2 g1 = make_float2(t1.x - t3.y, t1.y + t3.x);
  float2 h0 = cadd(wt5, w3t7);
  float2 h1 = cadd(wt7, w3t5);
  B[1] = cadd(g0, h0);
  B[5] = csub(g0, h0);
  B[3] = cadd(g1, h1);
  B[7] = csub(g1, h1);
}

// Radix-8 Stockham DIF butterfly j (span S), N=2048: twiddled stores to slice.
template<int S>
__device__ __forceinline__ void bf8(half2v* __restrict__ X, int sxor,
                                    const float2* __restrict__ twg,
                                    int j, const float2* a) {
  const int q = j & (S - 1);
  const int t = j - q;
  float2 B[8];
  dft8(a, B);
  float2 w1 = twg[t];          // exp(-2pi i t/2048), t < 256
  float2 w2 = cmul(w1, w1);
  float2 w3 = cmul(w2, w1);
  float2 w4 = cmul(w2, w2);
  float2 w5 = cmul(w3, w2);
  float2 w6 = cmul(w3, w3);
  float2 w7 = cmul(w4, w3);
  const int o = q + 8 * t;
  STH(X, SW(o) ^ sxor, B[0]);
  { float2 v = cmul(w1, B[1]); STH(X, SW(o + S)     ^ sxor, v); }
  { float2 v = cmul(w2, B[2]); STH(X, SW(o + 2 * S) ^ sxor, v); }
  { float2 v = cmul(w3, B[3]); STH(X, SW(o + 3 * S) ^ sxor, v); }
  { float2 v = cmul(w4, B[4]); STH(X, SW(o + 4 * S) ^ sxor, v); }
  { float2 v = cmul(w5, B[5]); STH(X, SW(o + 5 * S) ^ sxor, v); }
  { float2 v = cmul(w6, B[6]); STH(X, SW(o + 6 * S) ^ sxor, v); }
  { float2 v = cmul(w7, B[7]); STH(X, SW(o + 7 * S) ^ sxor, v); }
}

// load + window one frame into a[4][8] (lane l owns complex idx l+64r+256m)
__device__ __forceinline__ void loadwin(float2 (*a)[8], const float* __restrict__ xb,
                                        int f, int l,
                                        const float2* __restrict__ winv,
                                        const float* __restrict__ win) {
  const int base = f * HOPSZ - MHALF;
  if (base >= 0 && base + NFFT <= LX) {
    const float2* xv = (const float2*)(xb + base);  // base even -> aligned
#pragma unroll
    for (int r = 0; r < 4; ++r) {
      const int j = l + (r << 6);
#pragma unroll
      for (int m = 0; m < 8; ++m) {
        const int idx = j + (m << 8);
        float2 v = xv[idx];
        float2 w = winv[idx];
        a[r][m] = make_float2(v.x * w.x, v.y * w.y);
      }
    }
  } else {  // edge frames: per-element reflect
#pragma unroll
    for (int r = 0; r < 4; ++r) {
      const int j = l + (r << 6);
#pragma unroll
      for (int m = 0; m < 8; ++m) {
        const int idx = j + (m << 8);
        int s0 = base + 2 * idx;
        int s1 = s0 + 1;
        s0 = (s0 < 0) ? -s0 : ((s0 >= LX) ? (2 * LX - 2 - s0) : s0);
        s1 = (s1 < 0) ? -s1 : ((s1 >= LX) ? (2 * LX - 2 - s1) : s1);
        a[r][m] = make_float2(xb[s0] * win[2 * idx], xb[s1] * win[2 * idx + 1]);
      }
    }
  }
}

// Final radix-32 stage (S=64): externally twiddle-free; internal twiddles are
// compile-time W32 constants. dd = 32 regs after the dft4-over-m2 pass.
#define VBLK(dd, slp, sx, V) do {                                     \
    float2 tt[8], BB[8];                                              \
    tt[0] = dd[8*(V)+0];                                              \
    tt[1] = w32m<1*(V)>(dd[8*(V)+1]);                                 \
    tt[2] = w32m<2*(V)>(dd[8*(V)+2]);                                 \
    tt[3] = w32m<3*(V)>(dd[8*(V)+3]);                                 \
    tt[4] = w32m<4*(V)>(dd[8*(V)+4]);                                 \
    tt[5] = w32m<5*(V)>(dd[8*(V)+5]);                                 \
    tt[6] = w32m<6*(V)>(dd[8*(V)+6]);                                 \
    tt[7] = w32m<7*(V)>(dd[8*(V)+7]);                                 \
    dft8(tt, BB);                                                     \
    STH(slp, SW(l + (((V) +  0) << 6)) ^ sx, BB[0]);                  \
    STH(slp, SW(l + (((V) +  4) << 6)) ^ sx, BB[1]);                  \
    STH(slp, SW(l + (((V) +  8) << 6)) ^ sx, BB[2]);                  \
    STH(slp, SW(l + (((V) + 12) << 6)) ^ sx, BB[3]);                  \
    STH(slp, SW(l + (((V) + 16) << 6)) ^ sx, BB[4]);                  \
    STH(slp, SW(l + (((V) + 20) << 6)) ^ sx, BB[5]);                  \
    STH(slp, SW(l + (((V) + 24) << 6)) ^ sx, BB[6]);                  \
    STH(slp, SW(l + (((V) + 28) << 6)) ^ sx, BB[7]);                  \
  } while (0)

#define DFT4PASS(dd) do {                                             \
    _Pragma("unroll")                                                 \
    for (int m1 = 0; m1 < 8; ++m1) {                                  \
      float2 p0 = dd[m1], p1 = dd[m1 + 8], p2 = dd[m1 + 16], p3 = dd[m1 + 24]; \
      float2 e0 = cadd(p0, p2), e1 = csub(p0, p2);                    \
      float2 o0 = cadd(p1, p3), o1 = csub(p1, p3);                    \
      dd[m1]      = cadd(e0, o0);                                     \
      dd[m1 + 8]  = make_float2(e1.x + o1.y, e1.y - o1.x);            \
      dd[m1 + 16] = csub(e0, o0);                                     \
      dd[m1 + 24] = make_float2(e1.x - o1.y, e1.y + o1.x);            \
    }                                                                 \
  } while (0)

// 4 waves/block, TWO frames per wave (R9 geometry = 16 streams/CU, the
// measured optimum). FFT phase ordering relies on HW in-order same-wave LDS
// (compiler-only fences) -> no exposed lgkmcnt drains, full A/B interleave.
// One __syncthreads; R9's proven 8B per-frame-slot recomb stores.
__global__ __launch_bounds__(256, 2) void stft_fft(const float* __restrict__ x,
                                                   const float* __restrict__ ws,
                                                   float* __restrict__ out) {
  __shared__ half2v fbuf[NFPB * 2048];   // 64 KB

  const int tid = threadIdx.x;
  const int wid = (blockIdx.x & 7) * CH3 + (blockIdx.x >> 3);
  const int b  = wid / FBLK;
  const int fb = wid - b * FBLK;
  const int f0 = fb * NFPB;
  const int wv = tid >> 6;        // 0..3
  const int l  = tid & 63;
  const int fA = f0 + 2 * wv;     // always < NF
  const int fB = fA + 1;
  const bool hasB = (fB < NF);    // wave-uniform

  const float*  win  = ws;
  const float2* winv = (const float2*)ws;
  const float2* twg  = (const float2*)(ws + 4096);
  const float2* tw4  = (const float2*)(ws + 6144);
  const float* xb = x + (size_t)b * LX;

  half2v* __restrict__ slA = &fbuf[(2 * wv) * 2048];
  half2v* __restrict__ slB = &fbuf[(2 * wv + 1) * 2048];
  const int sxA = (2 * wv) << 2;
  const int sxB = (2 * wv + 1) << 2;

  {
    // ---- stage 1 (S=1): load+window -> regs -> twiddled LDS (A and B)
    float2 aA[4][8], aB[4][8];
    loadwin(aA, xb, fA, l, winv, win);
    if (hasB) loadwin(aB, xb, fB, l, winv, win);
#pragma unroll
    for (int r = 0; r < 4; ++r) {
      bf8<1>(slA, sxA, twg, l + (r << 6), aA[r]);
      if (hasB) bf8<1>(slB, sxB, twg, l + (r << 6), aB[r]);
    }
    SOFTSYNC();

    // ---- stage 2 (S=8): read-all(A,B) -> fence -> write-all(A,B)
#pragma unroll
    for (int r = 0; r < 4; ++r) {
      const int j = l + (r << 6);
#pragma unroll
      for (int m = 0; m < 8; ++m) {
        aA[r][m] = ldh(slA, SW(j + (m << 8)) ^ sxA);
        if (hasB) aB[r][m] = ldh(slB, SW(j + (m << 8)) ^ sxB);
      }
    }
    SOFTSYNC();
#pragma unroll
    for (int r = 0; r < 4; ++r) {
      bf8<8>(slA, sxA, twg, l + (r << 6), aA[r]);
      if (hasB) bf8<8>(slB, sxB, twg, l + (r << 6), aB[r]);
    }
    SOFTSYNC();
  }

  // ---- stage 3: radix-32 (S=64), lane-disjoint in-place, A and B
  {
    float2 dA[32], dB[32];
#pragma unroll
    for (int m = 0; m < 32; ++m) {
      dA[m] = ldh(slA, SW(l + (m << 6)) ^ sxA);
      if (hasB) dB[m] = ldh(slB, SW(l + (m << 6)) ^ sxB);
    }
    SOFTSYNC();
    DFT4PASS(dA);
    VBLK(dA, slA, sxA, 0); VBLK(dA, slA, sxA, 1);
    VBLK(dA, slA, sxA, 2); VBLK(dA, slA, sxA, 3);
    if (hasB) {
      DFT4PASS(dB);
      VBLK(dB, slB, sxB, 0); VBLK(dB, slB, sxB, 1);
      VBLK(dB, slB, sxB, 2); VBLK(dB, slB, sxB, 3);
    }
  }
  __syncthreads();   // the only block-wide barrier

  // ---- paired recomb + store: thread -> (k, frame-slot), 8B stores in
  // 64B-contiguous frame runs per k (R9-proven scheme).
  float2* __restrict__ op = (float2*)out;
  const size_t obB = (size_t)b * NK * NF;
  const int s  = tid & 7;           // frame slot
  const int kk = tid >> 3;          // 0..31
  const int fS = f0 + s;
  const bool act = (fS < NF);
  const half2v* __restrict__ sl2 = &fbuf[s * 2048];
  const int sx2 = s << 2;
#pragma unroll 4
  for (int it = 0; it < 32; ++it) {
    const int k  = kk + (it << 5);            // 0..1023
    const int km = (2048 - k) & 2047;
    float2 zk = ldh(sl2, SW(k)  ^ sx2);
    float2 zm = ldh(sl2, SW(km) ^ sx2);
    float xex = 0.5f * (zk.x + zm.x);
    float xey = 0.5f * (zk.y - zm.y);
    float xox = 0.5f * (zk.y + zm.y);
    float xoy = 0.5f * (zm.x - zk.x);
    float2 w = tw4[k];
    float tx = w.x * xox - w.y * xoy;
    float ty = w.x * xoy + w.y * xox;
    if (act) {
      op[obB + (size_t)k * NF + fS]          = make_float2(xex + tx,  xey + ty);
      op[obB + (size_t)(2048 - k) * NF + fS] = make_float2(xex - tx, -xey + ty);
    }
  }
  if (tid < 8 && (f0 + tid) < NF) {   // k = 1024: out = conj(z[1024])
    const half2v* slt = &fbuf[tid * 2048];
    float2 zq = ldh(slt, SW(1024) ^ (tid << 2));
    op[obB + (size_t)1024 * NF + (f0 + tid)] = make_float2(zq.x, -zq.y);
  }
}

extern "C" void kernel_launch(void* const* d_in, const int* in_sizes, int n_in,
                              void* d_out, int out_size, void* d_ws, size_t ws_size,
                              hipStream_t stream) {
  const float* x = (const float*)d_in[0];
  float* ws = (float*)d_ws;     // needs 10242 floats (~41 KB)
  float* out = (float*)d_out;
  stft_init<<<16, 256, 0, stream>>>(ws);
  stft_fft<<<NWG3, 256, 0, stream>>>(x, ws, out);
}